// Round 1
// baseline (3753.399 us; speedup 1.0000x reference)
//
#include <hip/hip_runtime.h>
#include <hip/hip_bf16.h>
#include <math.h>

#define NN 100000
#define EE 1600000
#define IN_F 128
#define HH 4
#define DD 32
#define LL 3

// ---------------------------------------------------------------------------
// Kernel 1: ft = x @ W  (N x 128 * 128 x 128), fused el/er attention dots.
// One block per node row, 128 threads (one per output column).
// W columns are read coalesced; x row staged in LDS.
// ---------------------------------------------------------------------------
__global__ void gemm_attn_kernel(const float* __restrict__ x,
                                 const float* __restrict__ W,
                                 const float* __restrict__ al,
                                 const float* __restrict__ ar,
                                 float* __restrict__ ft,
                                 float* __restrict__ el,
                                 float* __restrict__ er) {
    __shared__ float xs[IN_F];
    const int n = blockIdx.x;
    const int c = threadIdx.x;           // 0..127, = h*32 + d
    xs[c] = x[n * IN_F + c];
    __syncthreads();

    float acc = 0.f;
#pragma unroll 16
    for (int k = 0; k < IN_F; ++k) {
        acc = fmaf(xs[k], W[k * IN_F + c], acc);
    }
    ft[n * IN_F + c] = acc;

    // attention dots: reduce acc*al over the 32 lanes of each head
    float vl = acc * al[c];
    float vr = acc * ar[c];
#pragma unroll
    for (int off = 16; off >= 1; off >>= 1) {
        vl += __shfl_xor(vl, off);
        vr += __shfl_xor(vr, off);
    }
    if ((c & 31) == 0) {
        el[n * HH + (c >> 5)] = vl;
        er[n * HH + (c >> 5)] = vr;
    }
}

// ---------------------------------------------------------------------------
// Kernel 2: per edge, ee = exp(leaky_relu(el[src]+er[dst])); den[dst] += ee.
// One thread per edge handles all 4 heads (float4 loads/stores).
// Note: max-subtraction skipped — logits are tiny, softmax is invariant.
// ---------------------------------------------------------------------------
__global__ void edge_ee_kernel(const int* __restrict__ src,
                               const int* __restrict__ dst,
                               const float* __restrict__ el,
                               const float* __restrict__ er,
                               float* __restrict__ ee,
                               float* __restrict__ den) {
    const int e = blockIdx.x * blockDim.x + threadIdx.x;
    if (e >= EE) return;
    const int s = src[e];
    const int d = dst[e];
    const float4 l4 = ((const float4*)el)[s];
    const float4 r4 = ((const float4*)er)[d];
    float v[4] = {l4.x + r4.x, l4.y + r4.y, l4.z + r4.z, l4.w + r4.w};
    float4 o;
    float* op = &o.x;
#pragma unroll
    for (int h = 0; h < 4; ++h) {
        float t = v[h];
        t = t > 0.f ? t : 0.2f * t;      // leaky_relu slope 0.2
        float ex = expf(t);
        op[h] = ex;
        atomicAdd(&den[d * HH + h], ex);
    }
    ((float4*)ee)[e] = o;
}

// ---------------------------------------------------------------------------
// Kernel 3: message pass. One 64-lane wave per edge; lane l handles feature
// elements l and l+64. acc[dst] += ft[src] * a, a = ee/den.
// On the final layer also writes a (edge attention) to a_out.
// ---------------------------------------------------------------------------
__global__ void message_kernel(const float* __restrict__ ft,
                               const float* __restrict__ ee,
                               const float* __restrict__ den,
                               const int* __restrict__ src,
                               const int* __restrict__ dst,
                               float* __restrict__ acc,
                               float* __restrict__ a_out) {
    const int wave = (blockIdx.x * blockDim.x + threadIdx.x) >> 6;
    const int lane = threadIdx.x & 63;
    if (wave >= EE) return;
    const int s = src[wave];
    const int d = dst[wave];
    const int h0 = lane >> 5;            // head for element `lane` (0 or 1)
    const int h1 = h0 + 2;               // head for element `lane+64` (2 or 3)

    const float a0 = ee[wave * HH + h0] / fmaxf(den[d * HH + h0], 1e-9f);
    const float a1 = ee[wave * HH + h1] / fmaxf(den[d * HH + h1], 1e-9f);

    const float v0 = ft[s * IN_F + lane] * a0;
    const float v1 = ft[s * IN_F + 64 + lane] * a1;
    atomicAdd(&acc[d * IN_F + lane], v0);
    atomicAdd(&acc[d * IN_F + 64 + lane], v1);

    if (a_out != nullptr && lane < HH) {
        a_out[wave * HH + lane] = ee[wave * HH + lane] / fmaxf(den[d * HH + lane], 1e-9f);
    }
}

// ---------------------------------------------------------------------------
// Kernel 4: out = elu(acc + x_prev + bias)
// ---------------------------------------------------------------------------
__global__ void finalize_kernel(const float* __restrict__ acc,
                                const float* __restrict__ xprev,
                                const float* __restrict__ bias,
                                float* __restrict__ out) {
    const int i = blockIdx.x * blockDim.x + threadIdx.x;
    if (i >= NN * IN_F) return;
    float v = acc[i] + xprev[i] + bias[i & (IN_F - 1)];
    out[i] = v > 0.f ? v : expf(v) - 1.f;
}

extern "C" void kernel_launch(void* const* d_in, const int* in_sizes, int n_in,
                              void* d_out, int out_size, void* d_ws, size_t ws_size,
                              hipStream_t stream) {
    const float* h    = (const float*)d_in[0];
    const int*   src  = (const int*)  d_in[1];
    const int*   dst  = (const int*)  d_in[2];
    const float* Ws   = (const float*)d_in[3];
    const float* al   = (const float*)d_in[4];
    const float* ar   = (const float*)d_in[5];
    const float* bias = (const float*)d_in[6];

    float* out_x = (float*)d_out;                 // [N,128]
    float* out_a = out_x + (size_t)NN * IN_F;     // [E,4] — doubles as ee scratch

    char* ws = (char*)d_ws;
    float* ft   = (float*)ws;                          // N*128 floats
    float* bufA = ft + (size_t)NN * IN_F;              // N*128 floats
    float* el   = bufA + (size_t)NN * IN_F;            // N*4
    float* er   = el + (size_t)NN * HH;                // N*4
    float* den  = er + (size_t)NN * HH;                // N*4
    float* ee   = out_a;                               // E*4 (reuse out region)

    // layer schedule: x -> acc buffer -> finalized in place
    // L0: x=h,     acc=bufA,  out=bufA
    // L1: x=bufA,  acc=out_x, out=out_x
    // L2: x=out_x, acc=bufA,  out=out_x  (+ writes out_a)
    const float* xin[LL]  = {h, bufA, out_x};
    float*       accb[LL] = {bufA, out_x, bufA};
    float*       xout[LL] = {bufA, out_x, out_x};

    for (int i = 0; i < LL; ++i) {
        const float* Wl = Ws + (size_t)i * IN_F * IN_F;
        const float* all_ = al + (size_t)i * HH * DD;
        const float* arl = ar + (size_t)i * HH * DD;
        const float* bl  = bias + (size_t)i * HH * DD;

        hipMemsetAsync(accb[i], 0, (size_t)NN * IN_F * sizeof(float), stream);
        hipMemsetAsync(den, 0, (size_t)NN * HH * sizeof(float), stream);

        gemm_attn_kernel<<<NN, IN_F, 0, stream>>>(xin[i], Wl, all_, arl, ft, el, er);
        edge_ee_kernel<<<(EE + 255) / 256, 256, 0, stream>>>(src, dst, el, er, ee, den);
        message_kernel<<<EE / 4, 256, 0, stream>>>(ft, ee, den, src, dst, accb[i],
                                                   (i == LL - 1) ? out_a : nullptr);
        finalize_kernel<<<(NN * IN_F + 255) / 256, 256, 0, stream>>>(accb[i], xin[i], bl, xout[i]);
    }
}

// Round 2
// 1646.737 us; speedup vs baseline: 2.2793x; 2.2793x over previous
//
#include <hip/hip_runtime.h>
#include <hip/hip_bf16.h>
#include <math.h>

#define NN 100000
#define EE 1600000
#define IN_F 128
#define HH 4
#define DD 32
#define LL 3
#define NCH ((NN + 255) / 256)   // scan chunks = 391

// ---------------------------------------------------------------------------
// GEMM + attention dots: ft = x @ W, el/er head dots. One block per node.
// ---------------------------------------------------------------------------
__global__ void gemm_attn_kernel(const float* __restrict__ x,
                                 const float* __restrict__ W,
                                 const float* __restrict__ al,
                                 const float* __restrict__ ar,
                                 float* __restrict__ ft,
                                 float* __restrict__ el,
                                 float* __restrict__ er) {
    __shared__ float xs[IN_F];
    const int n = blockIdx.x;
    const int c = threadIdx.x;           // 0..127
    xs[c] = x[n * IN_F + c];
    __syncthreads();

    float acc = 0.f;
#pragma unroll 16
    for (int k = 0; k < IN_F; ++k) {
        acc = fmaf(xs[k], W[k * IN_F + c], acc);
    }
    ft[n * IN_F + c] = acc;

    float vl = acc * al[c];
    float vr = acc * ar[c];
#pragma unroll
    for (int off = 16; off >= 1; off >>= 1) {
        vl += __shfl_xor(vl, off);
        vr += __shfl_xor(vr, off);
    }
    if ((c & 31) == 0) {
        el[n * HH + (c >> 5)] = vl;
        er[n * HH + (c >> 5)] = vr;
    }
}

// ---------------------------------------------------------------------------
// CSR build: histogram, 2-level exclusive scan, scatter.
// ---------------------------------------------------------------------------
__global__ void hist_kernel(const int* __restrict__ dst, int* __restrict__ cnt) {
    const int e = blockIdx.x * blockDim.x + threadIdx.x;
    if (e < EE) atomicAdd(&cnt[dst[e]], 1);
}

__global__ void scan_chunk_kernel(const int* __restrict__ cnt,
                                  int* __restrict__ excl,
                                  int* __restrict__ chunk_sums) {
    __shared__ int tmp[256];
    const int tid = threadIdx.x;
    const int i = blockIdx.x * 256 + tid;
    int v = (i < NN) ? cnt[i] : 0;
    tmp[tid] = v;
    __syncthreads();
    for (int off = 1; off < 256; off <<= 1) {
        int t = (tid >= off) ? tmp[tid - off] : 0;
        __syncthreads();
        if (tid >= off) tmp[tid] += t;
        __syncthreads();
    }
    if (i < NN) excl[i] = tmp[tid] - v;
    if (tid == 255) chunk_sums[blockIdx.x] = tmp[255];
}

__global__ void scan_sums_kernel(int* __restrict__ chunk_sums) {
    __shared__ int tmp[512];
    const int tid = threadIdx.x;
    int v = (tid < NCH) ? chunk_sums[tid] : 0;
    tmp[tid] = v;
    __syncthreads();
    for (int off = 1; off < 512; off <<= 1) {
        int t = (tid >= off) ? tmp[tid - off] : 0;
        __syncthreads();
        if (tid >= off) tmp[tid] += t;
        __syncthreads();
    }
    if (tid < NCH) chunk_sums[tid] = tmp[tid] - v;   // exclusive
}

__global__ void scan_add_kernel(int* __restrict__ excl,
                                const int* __restrict__ chunk_sums) {
    const int i = blockIdx.x * 256 + threadIdx.x;
    if (i < NN) excl[i] += chunk_sums[blockIdx.x];
}

__global__ void scatter_kernel(const int* __restrict__ src,
                               const int* __restrict__ dst,
                               int* __restrict__ cursor,
                               int* __restrict__ ssrc,
                               int* __restrict__ eidx) {
    const int e = blockIdx.x * blockDim.x + threadIdx.x;
    if (e >= EE) return;
    const int d = dst[e];
    const int p = atomicAdd(&cursor[d], 1);
    ssrc[p] = src[e];
    eidx[p] = e;
}

// ---------------------------------------------------------------------------
// Fused aggregation: one 64-lane wave per dst node. Lane l handles feature
// elements l (head h0=l>>5) and l+64 (head h1=h0+2). In-register softmax
// numerator/denominator; fused residual + bias + ELU.
// ---------------------------------------------------------------------------
__global__ void aggregate_kernel(const float* __restrict__ ft,
                                 const float* __restrict__ el,
                                 const float* __restrict__ er,
                                 const float* __restrict__ xin,
                                 const float* __restrict__ bias,
                                 const int* __restrict__ row_start,
                                 const int* __restrict__ cnt,
                                 const int* __restrict__ ssrc,
                                 const int* __restrict__ eidx,
                                 float* __restrict__ out,
                                 float* __restrict__ den_arr,
                                 float* __restrict__ ee_out) {
    const int wave = (blockIdx.x * blockDim.x + threadIdx.x) >> 6;
    const int lane = threadIdx.x & 63;
    if (wave >= NN) return;
    const int n = wave;
    const int h0 = lane >> 5;
    const int h1 = h0 + 2;

    const float er0 = er[n * HH + h0];
    const float er1 = er[n * HH + h1];

    float acc0 = 0.f, acc1 = 0.f, den0 = 0.f, den1 = 0.f;
    const int beg = row_start[n];
    const int end = beg + cnt[n];
    for (int p = beg; p < end; ++p) {
        const int s = ssrc[p];
        float e0 = el[s * HH + h0] + er0;
        float e1 = el[s * HH + h1] + er1;
        e0 = e0 > 0.f ? e0 : 0.2f * e0;
        e1 = e1 > 0.f ? e1 : 0.2f * e1;
        const float ee0 = expf(e0);
        const float ee1 = expf(e1);
        den0 += ee0;
        den1 += ee1;
        acc0 = fmaf(ee0, ft[s * IN_F + lane], acc0);
        acc1 = fmaf(ee1, ft[s * IN_F + 64 + lane], acc1);
        if (ee_out != nullptr && (lane & 31) == 0) {
            const int e = eidx[p];
            ee_out[e * HH + h0] = ee0;
            ee_out[e * HH + h1] = ee1;
        }
    }

    if ((lane & 31) == 0) {
        den_arr[n * HH + h0] = den0;
        den_arr[n * HH + h1] = den1;
    }

    float v0 = acc0 / fmaxf(den0, 1e-9f) + xin[n * IN_F + lane] + bias[lane];
    float v1 = acc1 / fmaxf(den1, 1e-9f) + xin[n * IN_F + 64 + lane] + bias[64 + lane];
    out[n * IN_F + lane]      = v0 > 0.f ? v0 : expf(v0) - 1.f;
    out[n * IN_F + 64 + lane] = v1 > 0.f ? v1 : expf(v1) - 1.f;
}

// a_out[e,h] = ee[e,h] / den[dst[e],h]
__global__ void normalize_a_kernel(const int* __restrict__ dst,
                                   const float* __restrict__ den,
                                   float* __restrict__ a_out) {
    const int e = blockIdx.x * blockDim.x + threadIdx.x;
    if (e >= EE) return;
    const int d = dst[e];
    float4 a = ((float4*)a_out)[e];
    const float4 dn = ((const float4*)den)[d];
    a.x /= fmaxf(dn.x, 1e-9f);
    a.y /= fmaxf(dn.y, 1e-9f);
    a.z /= fmaxf(dn.z, 1e-9f);
    a.w /= fmaxf(dn.w, 1e-9f);
    ((float4*)a_out)[e] = a;
}

extern "C" void kernel_launch(void* const* d_in, const int* in_sizes, int n_in,
                              void* d_out, int out_size, void* d_ws, size_t ws_size,
                              hipStream_t stream) {
    const float* h    = (const float*)d_in[0];
    const int*   src  = (const int*)  d_in[1];
    const int*   dst  = (const int*)  d_in[2];
    const float* Ws   = (const float*)d_in[3];
    const float* al   = (const float*)d_in[4];
    const float* ar   = (const float*)d_in[5];
    const float* bias = (const float*)d_in[6];

    float* out_x = (float*)d_out;                 // [N,128]
    float* out_a = out_x + (size_t)NN * IN_F;     // [E,4]

    char* ws = (char*)d_ws;
    float* ft   = (float*)ws;                          // N*128
    float* bufA = ft + (size_t)NN * IN_F;              // N*128
    float* el   = bufA + (size_t)NN * IN_F;            // N*4
    float* er   = el + (size_t)NN * HH;                // N*4
    float* den  = er + (size_t)NN * HH;                // N*4
    int*   cnt        = (int*)(den + (size_t)NN * HH); // N
    int*   row_start  = cnt + NN;                      // N
    int*   cursor     = row_start + NN;                // N
    int*   chunk_sums = cursor + NN;                   // 512
    int*   ssrc       = chunk_sums + 512;              // E
    int*   eidx       = ssrc + EE;                     // E

    // ---- CSR build (identical every call) ----
    hipMemsetAsync(cnt, 0, NN * sizeof(int), stream);
    hist_kernel<<<(EE + 255) / 256, 256, 0, stream>>>(dst, cnt);
    scan_chunk_kernel<<<NCH, 256, 0, stream>>>(cnt, row_start, chunk_sums);
    scan_sums_kernel<<<1, 512, 0, stream>>>(chunk_sums);
    scan_add_kernel<<<NCH, 256, 0, stream>>>(row_start, chunk_sums);
    hipMemcpyAsync(cursor, row_start, NN * sizeof(int), hipMemcpyDeviceToDevice, stream);
    scatter_kernel<<<(EE + 255) / 256, 256, 0, stream>>>(src, dst, cursor, ssrc, eidx);

    // layer schedule: L0: h->bufA, L1: bufA->out_x, L2: out_x->out_x
    const float* xin[LL]  = {h, bufA, out_x};
    float*       xout[LL] = {bufA, out_x, out_x};

    for (int i = 0; i < LL; ++i) {
        const float* Wl  = Ws + (size_t)i * IN_F * IN_F;
        const float* all_ = al + (size_t)i * HH * DD;
        const float* arl = ar + (size_t)i * HH * DD;
        const float* bl  = bias + (size_t)i * HH * DD;

        gemm_attn_kernel<<<NN, IN_F, 0, stream>>>(xin[i], Wl, all_, arl, ft, el, er);
        aggregate_kernel<<<(NN + 3) / 4, 256, 0, stream>>>(
            ft, el, er, xin[i], bl, row_start, cnt, ssrc, eidx,
            xout[i], den, (i == LL - 1) ? out_a : nullptr);
    }
    normalize_a_kernel<<<(EE + 255) / 256, 256, 0, stream>>>(dst, den, out_a);
}

// Round 3
// 1301.678 us; speedup vs baseline: 2.8835x; 1.2651x over previous
//
#include <hip/hip_runtime.h>
#include <hip/hip_bf16.h>
#include <math.h>

#define NN 100000
#define EE 1600000
#define IN_F 128
#define HH 4
#define DD 32
#define LL 3
#define NCH ((NN + 255) / 256)   // scan chunks = 391
#define NPB 16                   // nodes per gemm block

// ---------------------------------------------------------------------------
// GEMM + attention dots. W staged in LDS (64KB), 16 nodes per block.
// ft stored as bf16 (gather payload); el/er computed from fp32 acc.
// ---------------------------------------------------------------------------
__global__ void gemm_attn_kernel(const float* __restrict__ x,
                                 const float* __restrict__ W,
                                 const float* __restrict__ al,
                                 const float* __restrict__ ar,
                                 __hip_bfloat16* __restrict__ ft_bf,
                                 float* __restrict__ el,
                                 float* __restrict__ er) {
    __shared__ float Wl[IN_F * IN_F];     // 64 KB
    __shared__ float xs[NPB][IN_F];       // 8 KB
    const int t = threadIdx.x;            // 0..255
    const int base = blockIdx.x * NPB;

    // stage W: 16384 floats as float4, 16 per thread
    const float4* W4 = (const float4*)W;
    float4* Wl4 = (float4*)Wl;
#pragma unroll
    for (int j = 0; j < 16; ++j) Wl4[j * 256 + t] = W4[j * 256 + t];
    // stage x: 16 rows x 128 = 512 float4, 2 per thread
    const float4* x4 = (const float4*)(x + (size_t)base * IN_F);
    float4* xs4 = (float4*)xs;
    xs4[t] = x4[t];
    xs4[256 + t] = x4[256 + t];
    __syncthreads();

    const int c = t & 127;                // output column
    const int sub = t >> 7;               // 0/1: which node of the pair
    const int hd = c >> 5;
    const float alc = al[c], arc = ar[c];

#pragma unroll
    for (int i = 0; i < NPB / 2; ++i) {
        const int nl = i * 2 + sub;
        float acc = 0.f;
#pragma unroll
        for (int k = 0; k < IN_F; ++k) {
            acc = fmaf(xs[nl][k], Wl[k * IN_F + c], acc);
        }
        const int n = base + nl;
        ft_bf[(size_t)n * IN_F + c] = __float2bfloat16(acc);

        float vl = acc * alc;
        float vr = acc * arc;
#pragma unroll
        for (int off = 16; off >= 1; off >>= 1) {
            vl += __shfl_xor(vl, off);
            vr += __shfl_xor(vr, off);
        }
        if ((c & 31) == 0) {
            el[n * HH + hd] = vl;
            er[n * HH + hd] = vr;
        }
    }
}

// ---------------------------------------------------------------------------
// CSR build: histogram, 2-level exclusive scan, scatter.
// ---------------------------------------------------------------------------
__global__ void hist_kernel(const int* __restrict__ dst, int* __restrict__ cnt) {
    const int e = blockIdx.x * blockDim.x + threadIdx.x;
    if (e < EE) atomicAdd(&cnt[dst[e]], 1);
}

__global__ void scan_chunk_kernel(const int* __restrict__ cnt,
                                  int* __restrict__ excl,
                                  int* __restrict__ chunk_sums) {
    __shared__ int tmp[256];
    const int tid = threadIdx.x;
    const int i = blockIdx.x * 256 + tid;
    int v = (i < NN) ? cnt[i] : 0;
    tmp[tid] = v;
    __syncthreads();
    for (int off = 1; off < 256; off <<= 1) {
        int t = (tid >= off) ? tmp[tid - off] : 0;
        __syncthreads();
        if (tid >= off) tmp[tid] += t;
        __syncthreads();
    }
    if (i < NN) excl[i] = tmp[tid] - v;
    if (tid == 255) chunk_sums[blockIdx.x] = tmp[255];
}

__global__ void scan_sums_kernel(int* __restrict__ chunk_sums) {
    __shared__ int tmp[512];
    const int tid = threadIdx.x;
    int v = (tid < NCH) ? chunk_sums[tid] : 0;
    tmp[tid] = v;
    __syncthreads();
    for (int off = 1; off < 512; off <<= 1) {
        int t = (tid >= off) ? tmp[tid - off] : 0;
        __syncthreads();
        if (tid >= off) tmp[tid] += t;
        __syncthreads();
    }
    if (tid < NCH) chunk_sums[tid] = tmp[tid] - v;   // exclusive
}

__global__ void scan_add_kernel(int* __restrict__ excl,
                                const int* __restrict__ chunk_sums) {
    const int i = blockIdx.x * 256 + threadIdx.x;
    if (i < NN) excl[i] += chunk_sums[blockIdx.x];
}

__global__ void scatter_kernel(const int* __restrict__ src,
                               const int* __restrict__ dst,
                               int* __restrict__ cursor,
                               int* __restrict__ ssrc,
                               int* __restrict__ eidx) {
    const int e = blockIdx.x * blockDim.x + threadIdx.x;
    if (e >= EE) return;
    const int d = dst[e];
    const int p = atomicAdd(&cursor[d], 1);
    ssrc[p] = src[e];
    eidx[p] = e;
}

// ---------------------------------------------------------------------------
// Fused aggregation: one 64-lane wave per dst node. Lane l handles feature
// elements 2l, 2l+1 (both in head l>>4) via one ushort2 bf16 gather word.
// In-register softmax num/den (fast __expf); fused residual + bias + ELU.
// ---------------------------------------------------------------------------
__global__ void aggregate_kernel(const __hip_bfloat16* __restrict__ ft_bf,
                                 const float* __restrict__ el,
                                 const float* __restrict__ er,
                                 const float* __restrict__ xin,
                                 const float* __restrict__ bias,
                                 const int* __restrict__ row_start,
                                 const int* __restrict__ cnt,
                                 const int* __restrict__ ssrc,
                                 const int* __restrict__ eidx,
                                 float* __restrict__ out,
                                 float* __restrict__ den_arr,
                                 float* __restrict__ a_out) {
    const int wave = (blockIdx.x * blockDim.x + threadIdx.x) >> 6;
    const int lane = threadIdx.x & 63;
    if (wave >= NN) return;
    const int n = wave;
    const int h = lane >> 4;                       // head for elems 2l,2l+1

    const float ern = er[n * HH + h];
    const unsigned int* ftw = (const unsigned int*)ft_bf;

    float acc0 = 0.f, acc1 = 0.f, den = 0.f;
    const int beg = row_start[n];
    const int end = beg + cnt[n];

    int p = beg;
    int s = (p < end) ? ssrc[p] : 0;
    while (p < end) {
        const int s_cur = s;
        const int pn = p + 1;
        if (pn < end) s = ssrc[pn];                // prefetch next src

        float ev = el[s_cur * HH + h] + ern;
        ev = ev > 0.f ? ev : 0.2f * ev;            // leaky_relu 0.2
        const float ee = __expf(ev);
        den += ee;

        const unsigned int w = ftw[(size_t)s_cur * 64 + lane];
        const float f0 = __uint_as_float(w << 16);
        const float f1 = __uint_as_float(w & 0xffff0000u);
        acc0 = fmaf(ee, f0, acc0);
        acc1 = fmaf(ee, f1, acc1);

        if (a_out != nullptr && (lane & 15) == 0) {
            a_out[(size_t)eidx[p] * HH + h] = ee;  // normalized later
        }
        p = pn;
    }

    if ((lane & 15) == 0) {
        den_arr[n * HH + h] = den;
    }

    const float inv = 1.f / fmaxf(den, 1e-9f);
    const float2 xi = ((const float2*)xin)[(size_t)n * 64 + lane];
    float v0 = acc0 * inv + xi.x + bias[2 * lane];
    float v1 = acc1 * inv + xi.y + bias[2 * lane + 1];
    v0 = v0 > 0.f ? v0 : __expf(v0) - 1.f;
    v1 = v1 > 0.f ? v1 : __expf(v1) - 1.f;
    ((float2*)out)[(size_t)n * 64 + lane] = make_float2(v0, v1);
}

// a_out[e,h] = ee[e,h] / den[dst[e],h]
__global__ void normalize_a_kernel(const int* __restrict__ dst,
                                   const float* __restrict__ den,
                                   float* __restrict__ a_out) {
    const int e = blockIdx.x * blockDim.x + threadIdx.x;
    if (e >= EE) return;
    const int d = dst[e];
    float4 a = ((float4*)a_out)[e];
    const float4 dn = ((const float4*)den)[d];
    a.x /= fmaxf(dn.x, 1e-9f);
    a.y /= fmaxf(dn.y, 1e-9f);
    a.z /= fmaxf(dn.z, 1e-9f);
    a.w /= fmaxf(dn.w, 1e-9f);
    ((float4*)a_out)[e] = a;
}

extern "C" void kernel_launch(void* const* d_in, const int* in_sizes, int n_in,
                              void* d_out, int out_size, void* d_ws, size_t ws_size,
                              hipStream_t stream) {
    const float* h    = (const float*)d_in[0];
    const int*   src  = (const int*)  d_in[1];
    const int*   dst  = (const int*)  d_in[2];
    const float* Ws   = (const float*)d_in[3];
    const float* al   = (const float*)d_in[4];
    const float* ar   = (const float*)d_in[5];
    const float* bias = (const float*)d_in[6];

    float* out_x = (float*)d_out;                 // [N,128]
    float* out_a = out_x + (size_t)NN * IN_F;     // [E,4]

    char* ws = (char*)d_ws;
    __hip_bfloat16* ft_bf = (__hip_bfloat16*)ws;           // N*128 bf16
    float* bufA = (float*)(ft_bf + (size_t)NN * IN_F);     // N*128 f32
    float* el   = bufA + (size_t)NN * IN_F;                // N*4
    float* er   = el + (size_t)NN * HH;                    // N*4
    float* den  = er + (size_t)NN * HH;                    // N*4
    int*   cnt        = (int*)(den + (size_t)NN * HH);     // N
    int*   row_start  = cnt + NN;                          // N
    int*   cursor     = row_start + NN;                    // N
    int*   chunk_sums = cursor + NN;                       // 512
    int*   ssrc       = chunk_sums + 512;                  // E
    int*   eidx       = ssrc + EE;                         // E

    // ---- CSR build (identical every call) ----
    hipMemsetAsync(cnt, 0, NN * sizeof(int), stream);
    hist_kernel<<<(EE + 255) / 256, 256, 0, stream>>>(dst, cnt);
    scan_chunk_kernel<<<NCH, 256, 0, stream>>>(cnt, row_start, chunk_sums);
    scan_sums_kernel<<<1, 512, 0, stream>>>(chunk_sums);
    scan_add_kernel<<<NCH, 256, 0, stream>>>(row_start, chunk_sums);
    hipMemcpyAsync(cursor, row_start, NN * sizeof(int), hipMemcpyDeviceToDevice, stream);
    scatter_kernel<<<(EE + 255) / 256, 256, 0, stream>>>(src, dst, cursor, ssrc, eidx);

    // layer schedule: L0: h->bufA, L1: bufA->out_x, L2: out_x->out_x
    const float* xin[LL]  = {h, bufA, out_x};
    float*       xout[LL] = {bufA, out_x, out_x};

    for (int i = 0; i < LL; ++i) {
        const float* Wl  = Ws + (size_t)i * IN_F * IN_F;
        const float* all_ = al + (size_t)i * HH * DD;
        const float* arl = ar + (size_t)i * HH * DD;
        const float* bl  = bias + (size_t)i * HH * DD;

        gemm_attn_kernel<<<NN / NPB, 256, 0, stream>>>(xin[i], Wl, all_, arl, ft_bf, el, er);
        aggregate_kernel<<<(NN + 3) / 4, 256, 0, stream>>>(
            ft_bf, el, er, xin[i], bl, row_start, cnt, ssrc, eidx,
            xout[i], den, (i == LL - 1) ? out_a : nullptr);
    }
    normalize_a_kernel<<<(EE + 255) / 256, 256, 0, stream>>>(dst, den, out_a);
}

// Round 4
// 745.912 us; speedup vs baseline: 5.0320x; 1.7451x over previous
//
#include <hip/hip_runtime.h>
#include <hip/hip_bf16.h>
#include <math.h>

#define NN 100000
#define EE 1600000
#define IN_F 128
#define HH 4
#define DD 32
#define LL 3
#define NCH ((NN + 255) / 256)   // scan chunks = 391

typedef __bf16 bf16x8 __attribute__((ext_vector_type(8)));
typedef float f32x4 __attribute__((ext_vector_type(4)));

static __device__ __forceinline__ unsigned short f2bf(float x) {
    __hip_bfloat16 b = __float2bfloat16(x);
    return *reinterpret_cast<unsigned short*>(&b);
}

// ---------------------------------------------------------------------------
// fp32 -> bf16 convert for the initial node features
// ---------------------------------------------------------------------------
__global__ void convert_h_kernel(const float* __restrict__ x,
                                 unsigned short* __restrict__ xb) {
    const int i = blockIdx.x * blockDim.x + threadIdx.x;   // over N*128/4
    if (i >= NN * 32) return;
    const float4 v = ((const float4*)x)[i];
    ushort4 o;
    o.x = f2bf(v.x); o.y = f2bf(v.y); o.z = f2bf(v.z); o.w = f2bf(v.w);
    ((ushort4*)xb)[i] = o;
}

// W [l][k][n] fp32 -> wt [l][n][k] bf16 (B-operand layout for MFMA)
__global__ void wt_kernel(const float* __restrict__ Ws,
                          unsigned short* __restrict__ wt) {
    const int i = blockIdx.x * blockDim.x + threadIdx.x;   // L*128*128
    if (i >= LL * IN_F * IN_F) return;
    const int l = i >> 14, r = i & 16383;
    const int n = r >> 7, k = r & 127;
    wt[i] = f2bf(Ws[(l << 14) + k * IN_F + n]);
}

// ---------------------------------------------------------------------------
// MFMA GEMM: ft = x @ W (bf16 in, fp32 acc), fused el/er dots from fp32 acc.
// One wave per 16 nodes; 8 N-tiles x 4 K-chunks of mfma_f32_16x16x32_bf16.
// A frag: A[m=lane&15][k=quad*8+j]; B frag: B[k=quad*8+j][n=lane&15] (from
// W^T [n][k]); C/D: row=quad*4+reg, col=lane&15.  (learn_hip m89/m120 maps)
// ---------------------------------------------------------------------------
__global__ __launch_bounds__(256) void gemm_mfma_kernel(
    const unsigned short* __restrict__ x_bf,
    const unsigned short* __restrict__ wt,    // [128 n][128 k] bf16
    const float* __restrict__ al,
    const float* __restrict__ ar,
    unsigned short* __restrict__ ft_bf,
    float* __restrict__ el,
    float* __restrict__ er) {
    const int wave = (blockIdx.x * blockDim.x + threadIdx.x) >> 6;
    const int lane = threadIdx.x & 63;
    const int base = wave * 16;
    if (base >= NN) return;
    const int c = lane & 15;
    const int quad = lane >> 4;

    const int arow = min(base + c, NN - 1);
    const bf16x8* ap = (const bf16x8*)(x_bf + (size_t)arow * IN_F);
    bf16x8 a[4];
#pragma unroll
    for (int kc = 0; kc < 4; ++kc) a[kc] = ap[kc * 4 + quad];

    f32x4 acc[8];
#pragma unroll
    for (int nt = 0; nt < 8; ++nt) {
        const bf16x8* bp = (const bf16x8*)(wt + (size_t)(nt * 16 + c) * IN_F);
        f32x4 d = {0.f, 0.f, 0.f, 0.f};
#pragma unroll
        for (int kc = 0; kc < 4; ++kc)
            d = __builtin_amdgcn_mfma_f32_16x16x32_bf16(a[kc], bp[kc * 4 + quad], d, 0, 0, 0);
        acc[nt] = d;
    }

    // ft store (bf16)
#pragma unroll
    for (int r = 0; r < 4; ++r) {
        const int n = base + quad * 4 + r;
        if (n < NN) {
#pragma unroll
            for (int nt = 0; nt < 8; ++nt)
                ft_bf[(size_t)n * IN_F + nt * 16 + c] = f2bf(acc[nt][r]);
        }
    }

    // attention dots from fp32 acc: head h covers tiles 2h, 2h+1
#pragma unroll
    for (int h = 0; h < 4; ++h) {
        float pl[4], pr[4];
#pragma unroll
        for (int r = 0; r < 4; ++r) {
            const float a0 = acc[2 * h][r], a1 = acc[2 * h + 1][r];
            pl[r] = a0 * al[h * 32 + c] + a1 * al[h * 32 + 16 + c];
            pr[r] = a0 * ar[h * 32 + c] + a1 * ar[h * 32 + 16 + c];
        }
#pragma unroll
        for (int off = 8; off >= 1; off >>= 1) {
#pragma unroll
            for (int r = 0; r < 4; ++r) {
                pl[r] += __shfl_xor(pl[r], off);
                pr[r] += __shfl_xor(pr[r], off);
            }
        }
        if (c == 0) {
#pragma unroll
            for (int r = 0; r < 4; ++r) {
                const int n = base + quad * 4 + r;
                if (n < NN) {
                    el[n * HH + h] = pl[r];
                    er[n * HH + h] = pr[r];
                }
            }
        }
    }
}

// ---------------------------------------------------------------------------
// CSR build: histogram, 2-level exclusive scan, scatter (src only).
// ---------------------------------------------------------------------------
__global__ void hist_kernel(const int* __restrict__ dst, int* __restrict__ cnt) {
    const int e = blockIdx.x * blockDim.x + threadIdx.x;
    if (e < EE) atomicAdd(&cnt[dst[e]], 1);
}

__global__ void scan_chunk_kernel(const int* __restrict__ cnt,
                                  int* __restrict__ excl,
                                  int* __restrict__ chunk_sums) {
    __shared__ int tmp[256];
    const int tid = threadIdx.x;
    const int i = blockIdx.x * 256 + tid;
    int v = (i < NN) ? cnt[i] : 0;
    tmp[tid] = v;
    __syncthreads();
    for (int off = 1; off < 256; off <<= 1) {
        int t = (tid >= off) ? tmp[tid - off] : 0;
        __syncthreads();
        if (tid >= off) tmp[tid] += t;
        __syncthreads();
    }
    if (i < NN) excl[i] = tmp[tid] - v;
    if (tid == 255) chunk_sums[blockIdx.x] = tmp[255];
}

__global__ void scan_sums_kernel(int* __restrict__ chunk_sums) {
    __shared__ int tmp[512];
    const int tid = threadIdx.x;
    int v = (tid < NCH) ? chunk_sums[tid] : 0;
    tmp[tid] = v;
    __syncthreads();
    for (int off = 1; off < 512; off <<= 1) {
        int t = (tid >= off) ? tmp[tid - off] : 0;
        __syncthreads();
        if (tid >= off) tmp[tid] += t;
        __syncthreads();
    }
    if (tid < NCH) chunk_sums[tid] = tmp[tid] - v;   // exclusive
}

__global__ void scan_add_kernel(int* __restrict__ excl,
                                const int* __restrict__ chunk_sums) {
    const int i = blockIdx.x * 256 + threadIdx.x;
    if (i < NN) excl[i] += chunk_sums[blockIdx.x];
}

__global__ void scatter_kernel(const int* __restrict__ src,
                               const int* __restrict__ dst,
                               int* __restrict__ cursor,
                               int* __restrict__ ssrc) {
    const int e = blockIdx.x * blockDim.x + threadIdx.x;
    if (e >= EE) return;
    const int p = atomicAdd(&cursor[dst[e]], 1);
    ssrc[p] = src[e];
}

// ---------------------------------------------------------------------------
// Fused aggregation: one wave per dst node, degree loop unrolled x4 for MLP.
// Lane l handles elems 2l,2l+1 (head l>>4). Fused /den, residual, bias, ELU;
// writes fp32 out + bf16 out (next layer's GEMM input).
// ---------------------------------------------------------------------------
__global__ void aggregate_kernel(const unsigned int* __restrict__ ftw,
                                 const float* __restrict__ el,
                                 const float* __restrict__ er,
                                 const float* __restrict__ xin,
                                 const float* __restrict__ bias,
                                 const int* __restrict__ row_start,
                                 const int* __restrict__ cnt,
                                 const int* __restrict__ ssrc,
                                 float* __restrict__ out,
                                 unsigned short* __restrict__ out_bf,
                                 float* __restrict__ den_arr) {
    const int n = (blockIdx.x * blockDim.x + threadIdx.x) >> 6;
    const int lane = threadIdx.x & 63;
    if (n >= NN) return;
    const int h = lane >> 4;

    const float ern = er[n * HH + h];
    float acc0 = 0.f, acc1 = 0.f, den = 0.f;
    const int beg = row_start[n];
    const int end = beg + cnt[n];

    int p = beg;
    for (; p + 4 <= end; p += 4) {
        int s[4];
#pragma unroll
        for (int j = 0; j < 4; ++j) s[j] = ssrc[p + j];
        float ee[4];
        unsigned int w[4];
#pragma unroll
        for (int j = 0; j < 4; ++j) {
            float ev = el[s[j] * HH + h] + ern;
            ev = ev > 0.f ? ev : 0.2f * ev;
            ee[j] = __expf(ev);
            w[j] = ftw[(size_t)s[j] * 64 + lane];
        }
#pragma unroll
        for (int j = 0; j < 4; ++j) {
            den += ee[j];
            acc0 = fmaf(ee[j], __uint_as_float(w[j] << 16), acc0);
            acc1 = fmaf(ee[j], __uint_as_float(w[j] & 0xffff0000u), acc1);
        }
    }
    for (; p < end; ++p) {
        const int s = ssrc[p];
        float ev = el[s * HH + h] + ern;
        ev = ev > 0.f ? ev : 0.2f * ev;
        const float e1 = __expf(ev);
        den += e1;
        const unsigned int w = ftw[(size_t)s * 64 + lane];
        acc0 = fmaf(e1, __uint_as_float(w << 16), acc0);
        acc1 = fmaf(e1, __uint_as_float(w & 0xffff0000u), acc1);
    }

    if ((lane & 15) == 0) den_arr[n * HH + h] = den;

    const float inv = 1.f / fmaxf(den, 1e-9f);
    const float2 xi = ((const float2*)xin)[(size_t)n * 64 + lane];
    float v0 = acc0 * inv + xi.x + bias[2 * lane];
    float v1 = acc1 * inv + xi.y + bias[2 * lane + 1];
    v0 = v0 > 0.f ? v0 : __expf(v0) - 1.f;
    v1 = v1 > 0.f ? v1 : __expf(v1) - 1.f;
    ((float2*)out)[(size_t)n * 64 + lane] = make_float2(v0, v1);
    ushort2 ob;
    ob.x = f2bf(v0); ob.y = f2bf(v1);
    ((ushort2*)out_bf)[(size_t)n * 64 + lane] = ob;
}

// ---------------------------------------------------------------------------
// a[e,h] = exp(leaky(el[src]+er[dst])) / den[dst]  (bit-identical __expf)
// ---------------------------------------------------------------------------
__global__ void attn_out_kernel(const int* __restrict__ src,
                                const int* __restrict__ dst,
                                const float* __restrict__ el,
                                const float* __restrict__ er,
                                const float* __restrict__ den,
                                float* __restrict__ a_out) {
    const int e = blockIdx.x * blockDim.x + threadIdx.x;
    if (e >= EE) return;
    const int s = src[e], d = dst[e];
    const float4 l4 = ((const float4*)el)[s];
    const float4 r4 = ((const float4*)er)[d];
    const float4 dn = ((const float4*)den)[d];
    float v[4] = {l4.x + r4.x, l4.y + r4.y, l4.z + r4.z, l4.w + r4.w};
    float dv[4] = {dn.x, dn.y, dn.z, dn.w};
    float4 o;
    float* op = &o.x;
#pragma unroll
    for (int hh = 0; hh < 4; ++hh) {
        float t = v[hh] > 0.f ? v[hh] : 0.2f * v[hh];
        op[hh] = __expf(t) / fmaxf(dv[hh], 1e-9f);
    }
    ((float4*)a_out)[e] = o;
}

extern "C" void kernel_launch(void* const* d_in, const int* in_sizes, int n_in,
                              void* d_out, int out_size, void* d_ws, size_t ws_size,
                              hipStream_t stream) {
    const float* h    = (const float*)d_in[0];
    const int*   src  = (const int*)  d_in[1];
    const int*   dst  = (const int*)  d_in[2];
    const float* Ws   = (const float*)d_in[3];
    const float* al   = (const float*)d_in[4];
    const float* ar   = (const float*)d_in[5];
    const float* bias = (const float*)d_in[6];

    float* out_x = (float*)d_out;                         // [N,128] fp32
    float* out_a = out_x + (size_t)NN * IN_F;             // [E,4] fp32
    // x_bf (N*128 bf16 = 25.6 MB) aliases the out_a region (E*4 f32 = 25.6 MB):
    // needed only during the layer loop; attn_out overwrites it at the end.
    unsigned short* x_bf = (unsigned short*)out_a;

    char* ws = (char*)d_ws;
    unsigned short* ft_bf = (unsigned short*)ws;              // N*128 bf16
    float* bufA = (float*)(ft_bf + (size_t)NN * IN_F);        // N*128 f32
    float* el   = bufA + (size_t)NN * IN_F;                   // N*4
    float* er   = el + (size_t)NN * HH;                       // N*4
    float* den  = er + (size_t)NN * HH;                       // N*4
    int*   cnt        = (int*)(den + (size_t)NN * HH);        // N
    int*   row_start  = cnt + NN;                             // N
    int*   cursor     = row_start + NN;                       // N
    int*   chunk_sums = cursor + NN;                          // 512
    int*   ssrc       = chunk_sums + 512;                     // E
    unsigned short* wt = (unsigned short*)(ssrc + EE);        // 3*128*128 bf16

    // ---- one-time conversions + CSR build (identical every call) ----
    convert_h_kernel<<<(NN * 32 + 255) / 256, 256, 0, stream>>>(h, x_bf);
    wt_kernel<<<(LL * IN_F * IN_F + 255) / 256, 256, 0, stream>>>(Ws, wt);

    hipMemsetAsync(cnt, 0, NN * sizeof(int), stream);
    hist_kernel<<<(EE + 255) / 256, 256, 0, stream>>>(dst, cnt);
    scan_chunk_kernel<<<NCH, 256, 0, stream>>>(cnt, row_start, chunk_sums);
    scan_sums_kernel<<<1, 512, 0, stream>>>(chunk_sums);
    scan_add_kernel<<<NCH, 256, 0, stream>>>(row_start, chunk_sums);
    hipMemcpyAsync(cursor, row_start, NN * sizeof(int), hipMemcpyDeviceToDevice, stream);
    scatter_kernel<<<(EE + 255) / 256, 256, 0, stream>>>(src, dst, cursor, ssrc);

    // layer schedule: L0: h->bufA, L1: bufA->out_x, L2: out_x->out_x
    const float* xin[LL]  = {h, bufA, out_x};
    float*       xout[LL] = {bufA, out_x, out_x};
    const int gemm_blocks = ((NN + 15) / 16 + 3) / 4;   // waves of 16 nodes, 4/block

    for (int i = 0; i < LL; ++i) {
        const float* all_ = al + (size_t)i * HH * DD;
        const float* arl = ar + (size_t)i * HH * DD;
        const float* bl  = bias + (size_t)i * HH * DD;

        gemm_mfma_kernel<<<gemm_blocks, 256, 0, stream>>>(
            x_bf, wt + (size_t)i * IN_F * IN_F, all_, arl, ft_bf, el, er);
        aggregate_kernel<<<(NN + 3) / 4, 256, 0, stream>>>(
            (const unsigned int*)ft_bf, el, er, xin[i], bl, row_start, cnt, ssrc,
            xout[i], x_bf, den);
    }
    attn_out_kernel<<<(EE + 255) / 256, 256, 0, stream>>>(src, dst, el, er, den, out_a);
}